// Round 14
// baseline (553.727 us; speedup 1.0000x reference)
//
#include <hip/hip_runtime.h>
#include <stdint.h>

typedef __attribute__((ext_vector_type(8))) short short8;
typedef __attribute__((ext_vector_type(4))) short short4v;
typedef __attribute__((ext_vector_type(4))) float floatx4;

__device__ __forceinline__ unsigned short f2bf(float x) {
  unsigned int u = __float_as_uint(x);
  u += 0x7fffu + ((u >> 16) & 1u);   // RNE
  return (unsigned short)(u >> 16);
}
__device__ __forceinline__ float bf2f(unsigned short b) {
  return __uint_as_float(((unsigned int)b) << 16);
}
// packed pair: two RNE bf16 in one u32 (pure int ops, no asm)
__device__ __forceinline__ unsigned int pk2bf(float lo, float hi) {
  return (unsigned int)f2bf(lo) | ((unsigned int)f2bf(hi) << 16);
}
// row swizzle: spreads same-column reads of consecutive rows across bank-quads.
__device__ __forceinline__ int sw3(int r) { return (r & 7) ^ (((r >> 3) & 1) * 3); }

// direct global->LDS (16B/lane). LDS dest = uniform base + lane*16 (linear);
// swizzle is applied on the per-lane GLOBAL address instead (m173 pattern).
__device__ __forceinline__ void gld16(const unsigned short* g, unsigned short* l) {
  __builtin_amdgcn_global_load_lds(
      (const __attribute__((address_space(1))) void*)g,
      (__attribute__((address_space(3))) void*)l, 16, 0, 0);
}

// ---- unified prologue: weight frags + h bf16 table, fully coalesced ----
// W1F/W2F B-frag layout: u=((k32*256+n)*4+kq)*8+j  holds W[k32*32+kq*8+j][n]
// W3F B-frag layout (N padded 2->16): u=(k32*64+L)*8+j holds W3[k32*32+(L>>4)*8+j][L&15] or 0
__global__ void prep_kernel(const float* __restrict__ h, const float* __restrict__ W1,
                            const float* __restrict__ W2, const float* __restrict__ W3,
                            unsigned short* __restrict__ HBF, unsigned short* __restrict__ W1F,
                            unsigned short* __restrict__ W2F, unsigned short* __restrict__ W3F,
                            int nh8) {
  const int t = threadIdx.x;
  int b = blockIdx.x;
  if (b < 512) {            // W1F: 131072 elems
    int u = b * 256 + t;
    int j = u & 7, kq = (u >> 3) & 3, n = (u >> 5) & 255, k32 = u >> 13;
    W1F[u] = f2bf(W1[(k32 * 32 + kq * 8 + j) * 256 + n]);
    return;
  }
  b -= 512;
  if (b < 256) {            // W2F: 65536 elems
    int u = b * 256 + t;
    int j = u & 7, kq = (u >> 3) & 3, n = (u >> 5) & 255, k32 = u >> 13;
    W2F[u] = f2bf(W2[(k32 * 32 + kq * 8 + j) * 256 + n]);
    return;
  }
  b -= 256;
  if (b < 16) {             // W3F: 4096 elems
    int u = b * 256 + t;
    int j = u & 7, L = (u >> 3) & 63, k32 = u >> 9;
    int n = L & 15, kq = L >> 4;
    W3F[u] = (n < 2) ? f2bf(W3[(k32 * 32 + kq * 8 + j) * 2 + n]) : (unsigned short)0;
    return;
  }
  b -= 16;
  int u = b * 256 + t;      // hcvt: 2x float4 -> 1x short8 (16B stores)
  if (u < nh8) {
    const float4* h4 = (const float4*)h;
    float4 v0 = h4[u * 2], v1 = h4[u * 2 + 1];
    short8 s;
    s[0] = (short)f2bf(v0.x); s[1] = (short)f2bf(v0.y);
    s[2] = (short)f2bf(v0.z); s[3] = (short)f2bf(v0.w);
    s[4] = (short)f2bf(v1.x); s[5] = (short)f2bf(v1.y);
    s[6] = (short)f2bf(v1.z); s[7] = (short)f2bf(v1.w);
    ((short8*)HBF)[u] = s;
  }
}

// ---- main kernel: 8 waves x acc[2][4] (32x64 tiles) -> 4 waves/SIMD ----
// R13 lesson (m69 quantum): waves/SIMD steps at reg totals {64,128,256};
// R11's 150-170 total (incl. 64 AGPR) rounds to 256 -> 2 waves/SIMD no
// matter the LDS. To hit the 128-class we need acc<=32: split the 64x256
// layer output across 8 waves as 2x4 tiles of 32x64 (wave w: rows
// (w&1)*32.., cols (w>>1)*64..). Unlike R6's acc[4][2] (which DOUBLED
// per-CU LDS A-reads -> flat), acc[2][4] keeps per-block A-reads/k-step at
// 16 == R11. B-loads double per block but waves w,w^1 share a col-slice
// within a k-step window -> L1-absorbed. Regs: 32 AGPR + bq[2][4](32) +
// ~50 misc ~= 115 <= 128 cap of (512,4). LDS P+S = 64.5 KB -> 2 blocks/CU
// x 8 waves = 16 waves/CU (2x R11). Plain __syncthreads (512-thr +
// counted-vmcnt is the R4/R5 untested-suspect combo; both gather halves
// issue together so the vmcnt(0) drain adds ~nothing). Compute/epilogue =
// R11's verified swapped-operand MFMA + packed 8B stores.
__global__ __launch_bounds__(512, 4)
void edge_mlp3(const unsigned short* __restrict__ hbf,
               const int* __restrict__ dst,
               const int* __restrict__ src,
               const unsigned short* __restrict__ W1F,
               const unsigned short* __restrict__ W2F,
               const unsigned short* __restrict__ W3F,
               float* __restrict__ out) {
  __shared__ __align__(16) unsigned short P[64 * 256];  // dst half; then X, X2
  __shared__ __align__(16) unsigned short S[64 * 256];  // src half
  __shared__ int ioff[128];

  const int t = threadIdx.x, lane = t & 63, w = t >> 6;  // w in 0..7
  const int lq = lane >> 4, lm = lane & 15;
  const int wr = (w & 1) * 32;        // row base of this wave's 32x64 tile
  const int wc = (w >> 1) * 64;       // col base
  const int m0 = blockIdx.x * 64;
  const int mm = lane & 31, rh = lane >> 5, rbase = w * 8;

  if (t < 64)       ioff[t] = dst[m0 + t];
  else if (t < 128) ioff[t] = src[m0 + t - 64];
  __syncthreads();   // ioff visible

  // ---- issue BOTH gather halves up-front: wave w owns rows [w*8, w*8+8)
  // of each half; 2 rows per gld16 (32 lanes per row).
#pragma unroll
  for (int tt = 0; tt < 4; ++tt) {
    int rl = rbase + 2 * tt + rh;
    int node = ioff[rl];
    gld16(hbf + (size_t)node * 256 + ((mm ^ sw3(rl)) << 3), &P[(rbase + 2 * tt) * 256]);
  }
#pragma unroll
  for (int tt = 0; tt < 4; ++tt) {
    int rl = rbase + 2 * tt + rh;
    int node = ioff[64 + rl];
    gld16(hbf + (size_t)node * 256 + ((mm ^ sw3(rl)) << 3), &S[(rbase + 2 * tt) * 256]);
  }

  floatx4 acc[2][4];
#pragma unroll
  for (int i = 0; i < 2; ++i)
#pragma unroll
    for (int j = 0; j < 4; ++j) acc[i][j] = (floatx4)(0.0f);

  const short8* B1 = (const short8*)W1F;
  const short8* B2 = (const short8*)W2F;

  __syncthreads();   // all gathers drained; P and S both resident

  // ---- layer1, k-steps 0..7 (dst features) on P; SWAPPED: mfma(bq, af, acc)
  {
    short8 bq[2][4];
#pragma unroll
    for (int jt = 0; jt < 4; ++jt) bq[0][jt] = B1[(0 * 256 + wc + jt * 16 + lm) * 4 + lq];
#pragma unroll
    for (int jt = 0; jt < 4; ++jt) bq[1][jt] = B1[(1 * 256 + wc + jt * 16 + lm) * 4 + lq];

#pragma unroll
    for (int s = 0; s < 8; ++s) {
#pragma unroll
      for (int i = 0; i < 2; ++i) {
        int r = wr + i * 16 + lm, c = s * 4 + lq;
        short8 af = *(const short8*)&P[r * 256 + ((c ^ sw3(r)) << 3)];
#pragma unroll
        for (int j = 0; j < 4; ++j)
          acc[i][j] = __builtin_amdgcn_mfma_f32_16x16x32_bf16(bq[s & 1][j], af, acc[i][j], 0, 0, 0);
      }
      if (s < 6)
#pragma unroll
        for (int jt = 0; jt < 4; ++jt)
          bq[s & 1][jt] = B1[((s + 2) * 256 + wc + jt * 16 + lm) * 4 + lq];
    }
  }
  __syncthreads();

  // ---- layer1, k-steps 8..15 (src features) on S
  {
    short8 bq[2][4];
#pragma unroll
    for (int jt = 0; jt < 4; ++jt) bq[0][jt] = B1[(8 * 256 + wc + jt * 16 + lm) * 4 + lq];
#pragma unroll
    for (int jt = 0; jt < 4; ++jt) bq[1][jt] = B1[(9 * 256 + wc + jt * 16 + lm) * 4 + lq];

#pragma unroll
    for (int s = 0; s < 8; ++s) {
#pragma unroll
      for (int i = 0; i < 2; ++i) {
        int r = wr + i * 16 + lm, c = s * 4 + lq;
        short8 af = *(const short8*)&S[r * 256 + ((c ^ sw3(r)) << 3)];
#pragma unroll
        for (int j = 0; j < 4; ++j)
          acc[i][j] = __builtin_amdgcn_mfma_f32_16x16x32_bf16(bq[s & 1][j], af, acc[i][j], 0, 0, 0);
      }
      if (s < 6)
#pragma unroll
        for (int jt = 0; jt < 4; ++jt)
          bq[s & 1][jt] = B1[((s + 10) * 256 + wc + jt * 16 + lm) * 4 + lq];
    }
  }
  // no barrier needed: E1 writes this wave's own (row,col) tile of P, and
  // P's last reads (L1-dst) are barrier-separated.

  // ---- Epilogue 1: relu -> X (=P). D^T map: lane holds edge row
  // wr+i*16+lm, 4 consecutive feature cols (wc + j*16 + lq*4 + rg).
#pragma unroll
  for (int i = 0; i < 2; ++i) {
    int row = wr + i * 16 + lm;
    int swz = sw3(row);
#pragma unroll
    for (int j = 0; j < 4; ++j) {
      int cb = wc + j * 16 + lq * 4;
      int c8 = cb >> 3, ce = cb & 7;
      float v0 = fmaxf(acc[i][j][0], 0.0f);
      float v1 = fmaxf(acc[i][j][1], 0.0f);
      float v2 = fmaxf(acc[i][j][2], 0.0f);
      float v3 = fmaxf(acc[i][j][3], 0.0f);
      uint2 pv;
      pv.x = pk2bf(v0, v1);
      pv.y = pk2bf(v2, v3);
      *(uint2*)&P[row * 256 + (((c8 ^ swz) << 3) | ce)] = pv;
    }
  }
#pragma unroll
  for (int i = 0; i < 2; ++i)
#pragma unroll
    for (int j = 0; j < 4; ++j) acc[i][j] = (floatx4)(0.0f);
  __syncthreads();   // X complete before L2 reads

  // ---- Layer 2: K=256, 8 k-steps, B-ring depth 2, reads X (=P), swapped
  {
    short8 bq[2][4];
#pragma unroll
    for (int jt = 0; jt < 4; ++jt) bq[0][jt] = B2[(0 * 256 + wc + jt * 16 + lm) * 4 + lq];
#pragma unroll
    for (int jt = 0; jt < 4; ++jt) bq[1][jt] = B2[(1 * 256 + wc + jt * 16 + lm) * 4 + lq];

#pragma unroll
    for (int s = 0; s < 8; ++s) {
#pragma unroll
      for (int i = 0; i < 2; ++i) {
        int r = wr + i * 16 + lm, c = s * 4 + lq;
        short8 af = *(const short8*)&P[r * 256 + ((c ^ sw3(r)) << 3)];
#pragma unroll
        for (int j = 0; j < 4; ++j)
          acc[i][j] = __builtin_amdgcn_mfma_f32_16x16x32_bf16(bq[s & 1][j], af, acc[i][j], 0, 0, 0);
      }
      if (s < 6)
#pragma unroll
        for (int jt = 0; jt < 4; ++jt)
          bq[s & 1][jt] = B2[((s + 2) * 256 + wc + jt * 16 + lm) * 4 + lq];
    }
  }
  __syncthreads();   // all X reads done before in-place X2 overwrite

  // ---- Epilogue 2: relu -> X2 (=P, in place), packed 8B stores
#pragma unroll
  for (int i = 0; i < 2; ++i) {
    int row = wr + i * 16 + lm;
    int swz = sw3(row);
#pragma unroll
    for (int j = 0; j < 4; ++j) {
      int cb = wc + j * 16 + lq * 4;
      int c8 = cb >> 3, ce = cb & 7;
      float v0 = fmaxf(acc[i][j][0], 0.0f);
      float v1 = fmaxf(acc[i][j][1], 0.0f);
      float v2 = fmaxf(acc[i][j][2], 0.0f);
      float v3 = fmaxf(acc[i][j][3], 0.0f);
      uint2 pv;
      pv.x = pk2bf(v0, v1);
      pv.y = pk2bf(v2, v3);
      *(uint2*)&P[row * 256 + (((c8 ^ swz) << 3) | ce)] = pv;
    }
  }
  __syncthreads();   // X2 complete before L3 reads

  // ---- Layer 3: out = X2 @ W3 via MFMA (N padded to 16; cols 0,1 valid)
  // tiny: waves 0..3 cover the 64 rows; waves 4..7 idle (no barrier inside).
  if (w < 4) {
    floatx4 a3 = (floatx4)(0.0f);
    const short8* B3 = (const short8*)W3F;
#pragma unroll
    for (int s = 0; s < 8; ++s) {
      short8 b3 = B3[s * 64 + lane];              // 1 KB coalesced, L2-hot
      int r = w * 16 + lm, cch = s * 4 + lq;
      short8 af = *(const short8*)&P[r * 256 + ((cch ^ sw3(r)) << 3)];
      a3 = __builtin_amdgcn_mfma_f32_16x16x32_bf16(af, b3, a3, 0, 0, 0);
    }
    if (lm < 2) {
#pragma unroll
      for (int rg = 0; rg < 4; ++rg)
        out[(m0 + w * 16 + lq * 4 + rg) * 2 + lm] = a3[rg];
    }
  }
}

// ---- legacy weight-frag kernel (fallback path only) ----
__global__ void wfrag_kernel(const float* __restrict__ W,
                             unsigned short* __restrict__ out, int total) {
  int u = blockIdx.x * 256 + threadIdx.x;
  if (u >= total) return;
  int j = u & 7, kq = (u >> 3) & 3, n = (u >> 5) & 255, k32 = u >> 13;
  out[u] = f2bf(W[(k32 * 32 + kq * 8 + j) * 256 + n]);
}

// ---- fp32-gather fallback (tiny workspace) ----
__global__ __launch_bounds__(256, 2)
void edge_mlp_fb(const float* __restrict__ h,
                 const int* __restrict__ dst,
                 const int* __restrict__ src,
                 const unsigned short* __restrict__ W1F,
                 const unsigned short* __restrict__ W2F,
                 const float* __restrict__ W3,
                 float* __restrict__ out) {
  __shared__ unsigned short A[64 * 512];
  __shared__ float w3s[512];
  __shared__ int ioff[128];
  unsigned short* X = A;
  const int t = threadIdx.x, lane = t & 63, w = t >> 6;
  const int lq = lane >> 4, lm = lane & 15;
  const int m0 = blockIdx.x * 64;
  if (t < 64) ioff[t] = dst[m0 + t];
  else if (t < 128) ioff[t] = src[m0 + t - 64];
  w3s[t] = W3[t];
  w3s[t + 256] = W3[t + 256];
  __syncthreads();
  {
    const int c = lane, half = (c >= 32) ? 64 : 0, cc = c & 31;
#pragma unroll
    for (int it = 0; it < 16; ++it) {
      int r = it * 4 + w;
      int node = ioff[half + r];
      const float4* h4 = (const float4*)h;
      float4 v0 = h4[node * 64 + cc * 2], v1 = h4[node * 64 + cc * 2 + 1];
      short8 v;
      v[0] = (short)f2bf(v0.x); v[1] = (short)f2bf(v0.y);
      v[2] = (short)f2bf(v0.z); v[3] = (short)f2bf(v0.w);
      v[4] = (short)f2bf(v1.x); v[5] = (short)f2bf(v1.y);
      v[6] = (short)f2bf(v1.z); v[7] = (short)f2bf(v1.w);
      *(short8*)&A[r * 512 + ((c ^ (r & 7)) << 3)] = v;
    }
  }
  floatx4 acc[4][4];
#pragma unroll
  for (int i = 0; i < 4; ++i)
#pragma unroll
    for (int j = 0; j < 4; ++j) acc[i][j] = (floatx4)(0.0f);
  __syncthreads();
  const short8* B1 = (const short8*)W1F;
  const short8* B2 = (const short8*)W2F;
#pragma unroll
  for (int k32 = 0; k32 < 16; ++k32) {
    short8 b[4], af[4];
#pragma unroll
    for (int jt = 0; jt < 4; ++jt)
      b[jt] = B1[(k32 * 256 + w * 64 + jt * 16 + lm) * 4 + lq];
#pragma unroll
    for (int i = 0; i < 4; ++i) {
      int r = i * 16 + lm, c = k32 * 4 + lq;
      af[i] = *(const short8*)&A[r * 512 + ((c ^ (r & 7)) << 3)];
    }
#pragma unroll
    for (int i = 0; i < 4; ++i)
#pragma unroll
      for (int j = 0; j < 4; ++j)
        acc[i][j] = __builtin_amdgcn_mfma_f32_16x16x32_bf16(af[i], b[j], acc[i][j], 0, 0, 0);
  }
  __syncthreads();
#pragma unroll
  for (int i = 0; i < 4; ++i) {
    int row0 = i * 16 + lq * 4;
#pragma unroll
    for (int j = 0; j < 4; ++j) {
      int col = w * 64 + j * 16 + lm, c8 = col >> 3, ce = col & 7;
#pragma unroll
      for (int rg = 0; rg < 4; ++rg) {
        int row = row0 + rg;
        float v = acc[i][j][rg];
        v = v > 0.0f ? v : 0.0f;
        X[row * 256 + (((c8 ^ (row & 7)) << 3) | ce)] = f2bf(v);
      }
    }
  }
#pragma unroll
  for (int i = 0; i < 4; ++i)
#pragma unroll
    for (int j = 0; j < 4; ++j) acc[i][j] = (floatx4)(0.0f);
  __syncthreads();
#pragma unroll
  for (int k32 = 0; k32 < 8; ++k32) {
    short8 b[4], af[4];
#pragma unroll
    for (int jt = 0; jt < 4; ++jt)
      b[jt] = B2[(k32 * 256 + w * 64 + jt * 16 + lm) * 4 + lq];
#pragma unroll
    for (int i = 0; i < 4; ++i) {
      int r = i * 16 + lm, c = k32 * 4 + lq;
      af[i] = *(const short8*)&X[r * 256 + ((c ^ (r & 7)) << 3)];
    }
#pragma unroll
    for (int i = 0; i < 4; ++i)
#pragma unroll
      for (int j = 0; j < 4; ++j)
        acc[i][j] = __builtin_amdgcn_mfma_f32_16x16x32_bf16(af[i], b[j], acc[i][j], 0, 0, 0);
  }
  __syncthreads();
#pragma unroll
  for (int i = 0; i < 4; ++i) {
    int row0 = i * 16 + lq * 4;
#pragma unroll
    for (int j = 0; j < 4; ++j) {
      int col = w * 64 + j * 16 + lm, c8 = col >> 3, ce = col & 7;
#pragma unroll
      for (int rg = 0; rg < 4; ++rg) {
        int row = row0 + rg;
        float v = acc[i][j][rg];
        v = v > 0.0f ? v : 0.0f;
        X[row * 256 + (((c8 ^ (row & 7)) << 3) | ce)] = f2bf(v);
      }
    }
  }
  __syncthreads();
  {
    int r = t >> 2, o = (t >> 1) & 1, hh = t & 1;
    float s = 0.0f;
#pragma unroll
    for (int it = 0; it < 16; ++it) {
      int c = hh * 16 + it;
      short8 xv = *(const short8*)&X[r * 256 + ((c ^ (r & 7)) << 3)];
#pragma unroll
      for (int e = 0; e < 8; ++e)
        s += bf2f((unsigned short)xv[e]) * w3s[((c << 3) + e) * 2 + o];
    }
    s += __shfl_xor(s, 1);
    if (hh == 0) out[(m0 + r) * 2 + o] = s;
  }
}

extern "C" void kernel_launch(void* const* d_in, const int* in_sizes, int n_in,
                              void* d_out, int out_size, void* d_ws, size_t ws_size,
                              hipStream_t stream) {
  const float* h   = (const float*)d_in[0];
  const int*   dst = (const int*)d_in[1];
  const int*   src = (const int*)d_in[2];
  const float* W1  = (const float*)d_in[3];
  const float* W2  = (const float*)d_in[4];
  const float* W3  = (const float*)d_in[5];
  float* out = (float*)d_out;

  const int h_elems = in_sizes[0];
  const int n_pairs = in_sizes[1];
  const int ntiles  = n_pairs / 64;

  const size_t hbf_elems = (size_t)h_elems;
  const bool use_hbf =
      ws_size >= (hbf_elems + 131072 + 65536 + 4096) * sizeof(unsigned short);

  unsigned short* HBF = (unsigned short*)d_ws;
  unsigned short* W1F = HBF + hbf_elems;
  unsigned short* W2F = W1F + 131072;
  unsigned short* W3F = W2F + 65536;

  if (use_hbf) {
    int nh8 = h_elems / 8;
    int grid = 512 + 256 + 16 + (nh8 + 255) / 256;
    prep_kernel<<<grid, 256, 0, stream>>>(h, W1, W2, W3, HBF, W1F, W2F, W3F, nh8);
    edge_mlp3<<<ntiles, 512, 0, stream>>>(HBF, dst, src, W1F, W2F, W3F, out);
  } else {
    unsigned short* W1Fb = (unsigned short*)d_ws;
    unsigned short* W2Fb = W1Fb + 131072;
    wfrag_kernel<<<512, 256, 0, stream>>>(W1, W1Fb, 131072);
    wfrag_kernel<<<256, 256, 0, stream>>>(W2, W2Fb, 65536);
    edge_mlp_fb<<<ntiles, 256, 0, stream>>>(h, dst, src, W1Fb, W2Fb, W3, out);
  }
}

// Round 16
// 432.892 us; speedup vs baseline: 1.2791x; 1.2791x over previous
//
#include <hip/hip_runtime.h>
#include <stdint.h>

typedef __attribute__((ext_vector_type(8))) short short8;
typedef __attribute__((ext_vector_type(4))) float floatx4;
typedef __attribute__((ext_vector_type(16))) float floatx16;

__device__ __forceinline__ unsigned short f2bf(float x) {
  unsigned int u = __float_as_uint(x);
  u += 0x7fffu + ((u >> 16) & 1u);   // RNE
  return (unsigned short)(u >> 16);
}
__device__ __forceinline__ float bf2f(unsigned short b) {
  return __uint_as_float(((unsigned int)b) << 16);
}
// packed pair: two RNE bf16 in one u32 (pure int ops, no asm)
__device__ __forceinline__ unsigned int pk2bf(float lo, float hi) {
  return (unsigned int)f2bf(lo) | ((unsigned int)f2bf(hi) << 16);
}
// row swizzle: spreads same-column reads of consecutive rows across bank-quads.
__device__ __forceinline__ int sw3(int r) { return (r & 7) ^ (((r >> 3) & 1) * 3); }

// direct global->LDS (16B/lane). LDS dest = uniform base + lane*16 (linear);
// swizzle is applied on the per-lane GLOBAL address instead (m173 pattern).
__device__ __forceinline__ void gld16(const unsigned short* g, unsigned short* l) {
  __builtin_amdgcn_global_load_lds(
      (const __attribute__((address_space(1))) void*)g,
      (__attribute__((address_space(3))) void*)l, 16, 0, 0);
}

// ---- unified prologue: weight frags + h bf16 table, fully coalesced ----
// W1F/W2F B-frag layout (32x32x16 MFMA): u=((k16*256+n)*2+q)*8+j holds
//   W[k16*16 + q*8 + j][n]   (q = lane>>5 half-K, j = element 0..7)
// W3F B-frag layout (16x16x32, N padded 2->16): u=(k32*64+L)*8+j holds
//   W3[k32*32+(L>>4)*8+j][L&15] or 0
__global__ void prep_kernel(const float* __restrict__ h, const float* __restrict__ W1,
                            const float* __restrict__ W2, const float* __restrict__ W3,
                            unsigned short* __restrict__ HBF, unsigned short* __restrict__ W1F,
                            unsigned short* __restrict__ W2F, unsigned short* __restrict__ W3F,
                            int nh8) {
  const int t = threadIdx.x;
  int b = blockIdx.x;
  if (b < 512) {            // W1F: 131072 elems, 32 k16-steps
    int u = b * 256 + t;
    int j = u & 7, q = (u >> 3) & 1, n = (u >> 4) & 255, k16 = u >> 12;
    W1F[u] = f2bf(W1[(k16 * 16 + q * 8 + j) * 256 + n]);
    return;
  }
  b -= 512;
  if (b < 256) {            // W2F: 65536 elems, 16 k16-steps
    int u = b * 256 + t;
    int j = u & 7, q = (u >> 3) & 1, n = (u >> 4) & 255, k16 = u >> 12;
    W2F[u] = f2bf(W2[(k16 * 16 + q * 8 + j) * 256 + n]);
    return;
  }
  b -= 256;
  if (b < 16) {             // W3F: 4096 elems (16x16 path, unchanged)
    int u = b * 256 + t;
    int j = u & 7, L = (u >> 3) & 63, k32 = u >> 9;
    int n = L & 15, kq = L >> 4;
    W3F[u] = (n < 2) ? f2bf(W3[(k32 * 32 + kq * 8 + j) * 2 + n]) : (unsigned short)0;
    return;
  }
  b -= 16;
  int u = b * 256 + t;      // hcvt: 2x float4 -> 1x short8 (16B stores)
  if (u < nh8) {
    const float4* h4 = (const float4*)h;
    float4 v0 = h4[u * 2], v1 = h4[u * 2 + 1];
    short8 s;
    s[0] = (short)f2bf(v0.x); s[1] = (short)f2bf(v0.y);
    s[2] = (short)f2bf(v0.z); s[3] = (short)f2bf(v0.w);
    s[4] = (short)f2bf(v1.x); s[5] = (short)f2bf(v1.y);
    s[6] = (short)f2bf(v1.z); s[7] = (short)f2bf(v1.w);
    ((short8*)HBF)[u] = s;
  }
}

// ---- main kernel: R11 skeleton + 32x32x16 MFMA for layers 1/2 ----
// R11 config is final for geometry (R1..R14: any route to >2 waves/SIMD
// starves the allocator or doubles LDS traffic). Change: layers 1/2 use
// v_mfma_f32_32x32x16_bf16, swapped operands mfma(W,X)=D^T. Per wave the
// same FLOPs = 192 MFMAs x ~8.1cyc (vs 384 x 4.85, -17% matrix time, and
// the k-loop instruction count halves: 4 MFMA + 2 ds_read + 2 B-loads per
// K=16 step). D^T map (m74/m101): lane holds edge row lane&31; regs
// 4g..4g+3 = 4 consecutive features g*8+4*(lane>>5) -> packed 8B epilogue
// stores survive. af granule = 2s+(lane>>5): 32 rows over 8 swizzled
// granules = 4-way bank aliasing (vs 8-way before). Gather, swizzle,
// counted vmcnt(8)+raw barrier, and the 16x16 layer 3 are unchanged.
// (R15 infra note: audited end-to-end after a double container failure --
// all frag maps verified vs m74/m101, all indices in bounds, uniform
// barriers; resubmitted unchanged per the R4->R6 protocol.)
__global__ __launch_bounds__(256, 2)
void edge_mlp3(const unsigned short* __restrict__ hbf,
               const int* __restrict__ dst,
               const int* __restrict__ src,
               const unsigned short* __restrict__ W1F,
               const unsigned short* __restrict__ W2F,
               const unsigned short* __restrict__ W3F,
               float* __restrict__ out) {
  __shared__ __align__(16) unsigned short P[64 * 256];  // dst half; then X, X2
  __shared__ __align__(16) unsigned short S[64 * 256];  // src half
  __shared__ int ioff[128];

  const int t = threadIdx.x, lane = t & 63, w = t >> 6;
  const int lq = lane >> 4, lm = lane & 15;   // 16x16 path (L3)
  const int ln = lane & 31, qh = lane >> 5;   // 32x32 path
  const int wc = w * 64;                      // wave col base
  const int m0 = blockIdx.x * 64;
  const int rbase = w * 16;

  if (t < 64)       ioff[t] = dst[m0 + t];
  else if (t < 128) ioff[t] = src[m0 + t - 64];
  __syncthreads();   // ioff visible; nothing else outstanding yet

  // ---- issue BOTH gather halves up-front: dst->P (oldest 8), src->S (newest 8)
#pragma unroll
  for (int tt = 0; tt < 8; ++tt) {
    int rl = rbase + 2 * tt + qh;
    int node = ioff[rl];
    gld16(hbf + (size_t)node * 256 + ((ln ^ sw3(rl)) << 3), &P[(rbase + 2 * tt) * 256]);
  }
#pragma unroll
  for (int tt = 0; tt < 8; ++tt) {
    int rl = rbase + 2 * tt + qh;
    int node = ioff[64 + rl];
    gld16(hbf + (size_t)node * 256 + ((ln ^ sw3(rl)) << 3), &S[(rbase + 2 * tt) * 256]);
  }

  floatx16 acc[2][2];
#pragma unroll
  for (int i = 0; i < 2; ++i)
#pragma unroll
    for (int j = 0; j < 2; ++j) acc[i][j] = (floatx16)(0.0f);

  const short8* B1 = (const short8*)W1F;
  const short8* B2 = (const short8*)W2F;

  // ---- counted wait: this wave's 8 dst loads landed; 8 src stay in flight
  asm volatile("s_waitcnt vmcnt(8)" ::: "memory");
  __builtin_amdgcn_sched_barrier(0);
  __builtin_amdgcn_s_barrier();      // RAW barrier: no vmcnt(0) drain
  __builtin_amdgcn_sched_barrier(0);

  // ---- layer1, k16-steps 0..15 (dst features) on P; mfma32(W, X) = D^T
  {
    short8 bq[2][2];
#pragma unroll
    for (int jt = 0; jt < 2; ++jt) bq[0][jt] = B1[((0 * 256 + wc + jt * 32 + ln) << 1) + qh];
#pragma unroll
    for (int jt = 0; jt < 2; ++jt) bq[1][jt] = B1[((1 * 256 + wc + jt * 32 + ln) << 1) + qh];

#pragma unroll
    for (int s = 0; s < 16; ++s) {
      short8 af[2];
#pragma unroll
      for (int i = 0; i < 2; ++i) {
        int r = i * 32 + ln;
        af[i] = *(const short8*)&P[r * 256 + (((2 * s + qh) ^ sw3(r)) << 3)];
      }
#pragma unroll
      for (int i = 0; i < 2; ++i)
#pragma unroll
        for (int j = 0; j < 2; ++j)
          acc[i][j] = __builtin_amdgcn_mfma_f32_32x32x16_bf16(bq[s & 1][j], af[i], acc[i][j], 0, 0, 0);
      if (s < 14)
#pragma unroll
        for (int jt = 0; jt < 2; ++jt)
          bq[s & 1][jt] = B1[(((s + 2) * 256 + wc + jt * 32 + ln) << 1) + qh];
    }
  }
  __syncthreads();   // vmcnt(0): src loads (already landed) + barrier

  // ---- layer1, k16-steps 16..31 (src features) on S
  {
    short8 bq[2][2];
#pragma unroll
    for (int jt = 0; jt < 2; ++jt) bq[0][jt] = B1[((16 * 256 + wc + jt * 32 + ln) << 1) + qh];
#pragma unroll
    for (int jt = 0; jt < 2; ++jt) bq[1][jt] = B1[((17 * 256 + wc + jt * 32 + ln) << 1) + qh];

#pragma unroll
    for (int s = 0; s < 16; ++s) {
      short8 af[2];
#pragma unroll
      for (int i = 0; i < 2; ++i) {
        int r = i * 32 + ln;
        af[i] = *(const short8*)&S[r * 256 + (((2 * s + qh) ^ sw3(r)) << 3)];
      }
#pragma unroll
      for (int i = 0; i < 2; ++i)
#pragma unroll
        for (int j = 0; j < 2; ++j)
          acc[i][j] = __builtin_amdgcn_mfma_f32_32x32x16_bf16(bq[s & 1][j], af[i], acc[i][j], 0, 0, 0);
      if (s < 14)
#pragma unroll
        for (int jt = 0; jt < 2; ++jt)
          bq[s & 1][jt] = B1[(((s + 18) * 256 + wc + jt * 32 + ln) << 1) + qh];
    }
  }
  // no barrier needed: E1 uses only this wave's acc, writes its own col
  // range of P, and P's last reads (L1-dst) are barrier-separated.

  // ---- Epilogue 1: relu -> X (=P). D^T map: lane = edge row i*32+ln;
  // regs 4g..4g+3 = features wc + j*32 + g*8 + 4*qh + (0..3). Pack + 8B.
#pragma unroll
  for (int i = 0; i < 2; ++i) {
    int r = i * 32 + ln;
    int swz = sw3(r);
#pragma unroll
    for (int j = 0; j < 2; ++j) {
#pragma unroll
      for (int g = 0; g < 4; ++g) {
        int c8 = (wc >> 3) + j * 4 + g;
        float v0 = fmaxf(acc[i][j][4 * g + 0], 0.0f);
        float v1 = fmaxf(acc[i][j][4 * g + 1], 0.0f);
        float v2 = fmaxf(acc[i][j][4 * g + 2], 0.0f);
        float v3 = fmaxf(acc[i][j][4 * g + 3], 0.0f);
        uint2 pv;
        pv.x = pk2bf(v0, v1);
        pv.y = pk2bf(v2, v3);
        *(uint2*)&P[r * 256 + (((c8 ^ swz) << 3) | (qh << 2))] = pv;
      }
    }
  }
#pragma unroll
  for (int i = 0; i < 2; ++i)
#pragma unroll
    for (int j = 0; j < 2; ++j) acc[i][j] = (floatx16)(0.0f);
  __syncthreads();   // X complete before L2 reads

  // ---- Layer 2: K=256, 16 k16-steps, reads X (=P), mfma32 swapped
  {
    short8 bq[2][2];
#pragma unroll
    for (int jt = 0; jt < 2; ++jt) bq[0][jt] = B2[((0 * 256 + wc + jt * 32 + ln) << 1) + qh];
#pragma unroll
    for (int jt = 0; jt < 2; ++jt) bq[1][jt] = B2[((1 * 256 + wc + jt * 32 + ln) << 1) + qh];

#pragma unroll
    for (int s = 0; s < 16; ++s) {
      short8 af[2];
#pragma unroll
      for (int i = 0; i < 2; ++i) {
        int r = i * 32 + ln;
        af[i] = *(const short8*)&P[r * 256 + (((2 * s + qh) ^ sw3(r)) << 3)];
      }
#pragma unroll
      for (int i = 0; i < 2; ++i)
#pragma unroll
        for (int j = 0; j < 2; ++j)
          acc[i][j] = __builtin_amdgcn_mfma_f32_32x32x16_bf16(bq[s & 1][j], af[i], acc[i][j], 0, 0, 0);
      if (s < 14)
#pragma unroll
        for (int jt = 0; jt < 2; ++jt)
          bq[s & 1][jt] = B2[(((s + 2) * 256 + wc + jt * 32 + ln) << 1) + qh];
    }
  }
  __syncthreads();   // all X reads done before in-place X2 overwrite

  // ---- Epilogue 2: relu -> X2 (=P, in place), packed 8B stores
#pragma unroll
  for (int i = 0; i < 2; ++i) {
    int r = i * 32 + ln;
    int swz = sw3(r);
#pragma unroll
    for (int j = 0; j < 2; ++j) {
#pragma unroll
      for (int g = 0; g < 4; ++g) {
        int c8 = (wc >> 3) + j * 4 + g;
        float v0 = fmaxf(acc[i][j][4 * g + 0], 0.0f);
        float v1 = fmaxf(acc[i][j][4 * g + 1], 0.0f);
        float v2 = fmaxf(acc[i][j][4 * g + 2], 0.0f);
        float v3 = fmaxf(acc[i][j][4 * g + 3], 0.0f);
        uint2 pv;
        pv.x = pk2bf(v0, v1);
        pv.y = pk2bf(v2, v3);
        *(uint2*)&P[r * 256 + (((c8 ^ swz) << 3) | (qh << 2))] = pv;
      }
    }
  }
  __syncthreads();   // X2 complete before L3 reads

  // ---- Layer 3: out = X2 @ W3 via 16x16 MFMA (N padded to 16) -- unchanged
  {
    floatx4 a3 = (floatx4)(0.0f);
    const short8* B3 = (const short8*)W3F;
#pragma unroll
    for (int s = 0; s < 8; ++s) {
      short8 b3 = B3[s * 64 + lane];              // 1 KB coalesced, L2-hot
      int r = w * 16 + lm, cch = s * 4 + lq;
      short8 af = *(const short8*)&P[r * 256 + ((cch ^ sw3(r)) << 3)];
      a3 = __builtin_amdgcn_mfma_f32_16x16x32_bf16(af, b3, a3, 0, 0, 0);
    }
    if (lm < 2) {
#pragma unroll
      for (int rg = 0; rg < 4; ++rg)
        out[(m0 + w * 16 + lq * 4 + rg) * 2 + lm] = a3[rg];
    }
  }
}

// ---- legacy weight-frag kernel (fallback path only, 16x16 layout) ----
__global__ void wfrag_kernel(const float* __restrict__ W,
                             unsigned short* __restrict__ out, int total) {
  int u = blockIdx.x * 256 + threadIdx.x;
  if (u >= total) return;
  int j = u & 7, kq = (u >> 3) & 3, n = (u >> 5) & 255, k32 = u >> 13;
  out[u] = f2bf(W[(k32 * 32 + kq * 8 + j) * 256 + n]);
}

// ---- fp32-gather fallback (tiny workspace) ----
__global__ __launch_bounds__(256, 2)
void edge_mlp_fb(const float* __restrict__ h,
                 const int* __restrict__ dst,
                 const int* __restrict__ src,
                 const unsigned short* __restrict__ W1F,
                 const unsigned short* __restrict__ W2F,
                 const float* __restrict__ W3,
                 float* __restrict__ out) {
  __shared__ unsigned short A[64 * 512];
  __shared__ float w3s[512];
  __shared__ int ioff[128];
  unsigned short* X = A;
  const int t = threadIdx.x, lane = t & 63, w = t >> 6;
  const int lq = lane >> 4, lm = lane & 15;
  const int m0 = blockIdx.x * 64;
  if (t < 64) ioff[t] = dst[m0 + t];
  else if (t < 128) ioff[t] = src[m0 + t - 64];
  w3s[t] = W3[t];
  w3s[t + 256] = W3[t + 256];
  __syncthreads();
  {
    const int c = lane, half = (c >= 32) ? 64 : 0, cc = c & 31;
#pragma unroll
    for (int it = 0; it < 16; ++it) {
      int r = it * 4 + w;
      int node = ioff[half + r];
      const float4* h4 = (const float4*)h;
      float4 v0 = h4[node * 64 + cc * 2], v1 = h4[node * 64 + cc * 2 + 1];
      short8 v;
      v[0] = (short)f2bf(v0.x); v[1] = (short)f2bf(v0.y);
      v[2] = (short)f2bf(v0.z); v[3] = (short)f2bf(v0.w);
      v[4] = (short)f2bf(v1.x); v[5] = (short)f2bf(v1.y);
      v[6] = (short)f2bf(v1.z); v[7] = (short)f2bf(v1.w);
      *(short8*)&A[r * 512 + ((c ^ (r & 7)) << 3)] = v;
    }
  }
  floatx4 acc[4][4];
#pragma unroll
  for (int i = 0; i < 4; ++i)
#pragma unroll
    for (int j = 0; j < 4; ++j) acc[i][j] = (floatx4)(0.0f);
  __syncthreads();
  const short8* B1 = (const short8*)W1F;
  const short8* B2 = (const short8*)W2F;
#pragma unroll
  for (int k32 = 0; k32 < 16; ++k32) {
    short8 b[4], af[4];
#pragma unroll
    for (int jt = 0; jt < 4; ++jt)
      b[jt] = B1[(k32 * 256 + w * 64 + jt * 16 + lm) * 4 + lq];
#pragma unroll
    for (int i = 0; i < 4; ++i) {
      int r = i * 16 + lm, c = k32 * 4 + lq;
      af[i] = *(const short8*)&A[r * 512 + ((c ^ (r & 7)) << 3)];
    }
#pragma unroll
    for (int i = 0; i < 4; ++i)
#pragma unroll
      for (int j = 0; j < 4; ++j)
        acc[i][j] = __builtin_amdgcn_mfma_f32_16x16x32_bf16(af[i], b[j], acc[i][j], 0, 0, 0);
  }
  __syncthreads();
#pragma unroll
  for (int i = 0; i < 4; ++i) {
    int row0 = i * 16 + lq * 4;
#pragma unroll
    for (int j = 0; j < 4; ++j) {
      int col = w * 64 + j * 16 + lm, c8 = col >> 3, ce = col & 7;
#pragma unroll
      for (int rg = 0; rg < 4; ++rg) {
        int row = row0 + rg;
        float v = acc[i][j][rg];
        v = v > 0.0f ? v : 0.0f;
        X[row * 256 + (((c8 ^ (row & 7)) << 3) | ce)] = f2bf(v);
      }
    }
  }
#pragma unroll
  for (int i = 0; i < 4; ++i)
#pragma unroll
    for (int j = 0; j < 4; ++j) acc[i][j] = (floatx4)(0.0f);
  __syncthreads();
#pragma unroll
  for (int k32 = 0; k32 < 8; ++k32) {
    short8 b[4], af[4];
#pragma unroll
    for (int jt = 0; jt < 4; ++jt)
      b[jt] = B2[(k32 * 256 + w * 64 + jt * 16 + lm) * 4 + lq];
#pragma unroll
    for (int i = 0; i < 4; ++i) {
      int r = i * 16 + lm, c = k32 * 4 + lq;
      af[i] = *(const short8*)&X[r * 256 + ((c ^ (r & 7)) << 3)];
    }
#pragma unroll
    for (int i = 0; i < 4; ++i)
#pragma unroll
      for (int j = 0; j < 4; ++j)
        acc[i][j] = __builtin_amdgcn_mfma_f32_16x16x32_bf16(af[i], b[j], acc[i][j], 0, 0, 0);
  }
  __syncthreads();
#pragma unroll
  for (int i = 0; i < 4; ++i) {
    int row0 = i * 16 + lq * 4;
#pragma unroll
    for (int j = 0; j < 4; ++j) {
      int col = w * 64 + j * 16 + lm, c8 = col >> 3, ce = col & 7;
#pragma unroll
      for (int rg = 0; rg < 4; ++rg) {
        int row = row0 + rg;
        float v = acc[i][j][rg];
        v = v > 0.0f ? v : 0.0f;
        X[row * 256 + (((c8 ^ (row & 7)) << 3) | ce)] = f2bf(v);
      }
    }
  }
  __syncthreads();
  {
    int r = t >> 2, o = (t >> 1) & 1, hh = t & 1;
    float s = 0.0f;
#pragma unroll
    for (int it = 0; it < 16; ++it) {
      int c = hh * 16 + it;
      short8 xv = *(const short8*)&X[r * 256 + ((c ^ (r & 7)) << 3)];
#pragma unroll
      for (int e = 0; e < 8; ++e)
        s += bf2f((unsigned short)xv[e]) * w3s[((c << 3) + e) * 2 + o];
    }
    s += __shfl_xor(s, 1);
    if (hh == 0) out[(m0 + r) * 2 + o] = s;
  }
}

extern "C" void kernel_launch(void* const* d_in, const int* in_sizes, int n_in,
                              void* d_out, int out_size, void* d_ws, size_t ws_size,
                              hipStream_t stream) {
  const float* h   = (const float*)d_in[0];
  const int*   dst = (const int*)d_in[1];
  const int*   src = (const int*)d_in[2];
  const float* W1  = (const float*)d_in[3];
  const float* W2  = (const float*)d_in[4];
  const float* W3  = (const float*)d_in[5];
  float* out = (float*)d_out;

  const int h_elems = in_sizes[0];
  const int n_pairs = in_sizes[1];
  const int ntiles  = n_pairs / 64;

  const size_t hbf_elems = (size_t)h_elems;
  const bool use_hbf =
      ws_size >= (hbf_elems + 131072 + 65536 + 4096) * sizeof(unsigned short);

  unsigned short* HBF = (unsigned short*)d_ws;
  unsigned short* W1F = HBF + hbf_elems;
  unsigned short* W2F = W1F + 131072;
  unsigned short* W3F = W2F + 65536;

  if (use_hbf) {
    int nh8 = h_elems / 8;
    int grid = 512 + 256 + 16 + (nh8 + 255) / 256;
    prep_kernel<<<grid, 256, 0, stream>>>(h, W1, W2, W3, HBF, W1F, W2F, W3F, nh8);
    edge_mlp3<<<ntiles, 256, 0, stream>>>(HBF, dst, src, W1F, W2F, W3F, out);
  } else {
    unsigned short* W1Fb = (unsigned short*)d_ws;
    unsigned short* W2Fb = W1Fb + 131072;
    wfrag_kernel<<<512, 256, 0, stream>>>(W1, W1Fb, 131072);
    wfrag_kernel<<<256, 256, 0, stream>>>(W2, W2Fb, 65536);
    edge_mlp_fb<<<ntiles, 256, 0, stream>>>(h, dst, src, W1Fb, W2Fb, W3, out);
  }
}

// Round 17
// 428.315 us; speedup vs baseline: 1.2928x; 1.0107x over previous
//
#include <hip/hip_runtime.h>
#include <stdint.h>

typedef __attribute__((ext_vector_type(8))) short short8;
typedef __attribute__((ext_vector_type(4))) float floatx4;
typedef __attribute__((ext_vector_type(16))) float floatx16;

__device__ __forceinline__ unsigned short f2bf(float x) {
  unsigned int u = __float_as_uint(x);
  u += 0x7fffu + ((u >> 16) & 1u);   // RNE
  return (unsigned short)(u >> 16);
}
__device__ __forceinline__ float bf2f(unsigned short b) {
  return __uint_as_float(((unsigned int)b) << 16);
}
// packed pair: two RNE bf16 in one u32 (pure int ops, no asm)
__device__ __forceinline__ unsigned int pk2bf(float lo, float hi) {
  return (unsigned int)f2bf(lo) | ((unsigned int)f2bf(hi) << 16);
}
// row swizzle: spreads same-column reads of consecutive rows across bank-quads.
__device__ __forceinline__ int sw3(int r) { return (r & 7) ^ (((r >> 3) & 1) * 3); }

// direct global->LDS (16B/lane). LDS dest = uniform base + lane*16 (linear);
// swizzle is applied on the per-lane GLOBAL address instead (m173 pattern).
__device__ __forceinline__ void gld16(const unsigned short* g, unsigned short* l) {
  __builtin_amdgcn_global_load_lds(
      (const __attribute__((address_space(1))) void*)g,
      (__attribute__((address_space(3))) void*)l, 16, 0, 0);
}

// ---- unified prologue: weight frags + h bf16 table, fully coalesced ----
// W1F/W2F B-frag layout (32x32x16 MFMA): u=((k16*256+n)*2+q)*8+j holds
//   W[k16*16 + q*8 + j][n]   (q = lane>>5 half-K, j = element 0..7)
// W3F B-frag layout (16x16x32, N padded 2->16): u=(k32*64+L)*8+j holds
//   W3[k32*32+(L>>4)*8+j][L&15] or 0
__global__ void prep_kernel(const float* __restrict__ h, const float* __restrict__ W1,
                            const float* __restrict__ W2, const float* __restrict__ W3,
                            unsigned short* __restrict__ HBF, unsigned short* __restrict__ W1F,
                            unsigned short* __restrict__ W2F, unsigned short* __restrict__ W3F,
                            int nh8) {
  const int t = threadIdx.x;
  int b = blockIdx.x;
  if (b < 512) {            // W1F: 131072 elems, 32 k16-steps
    int u = b * 256 + t;
    int j = u & 7, q = (u >> 3) & 1, n = (u >> 4) & 255, k16 = u >> 12;
    W1F[u] = f2bf(W1[(k16 * 16 + q * 8 + j) * 256 + n]);
    return;
  }
  b -= 512;
  if (b < 256) {            // W2F: 65536 elems, 16 k16-steps
    int u = b * 256 + t;
    int j = u & 7, q = (u >> 3) & 1, n = (u >> 4) & 255, k16 = u >> 12;
    W2F[u] = f2bf(W2[(k16 * 16 + q * 8 + j) * 256 + n]);
    return;
  }
  b -= 256;
  if (b < 16) {             // W3F: 4096 elems (16x16 path, unchanged)
    int u = b * 256 + t;
    int j = u & 7, L = (u >> 3) & 63, k32 = u >> 9;
    int n = L & 15, kq = L >> 4;
    W3F[u] = (n < 2) ? f2bf(W3[(k32 * 32 + kq * 8 + j) * 2 + n]) : (unsigned short)0;
    return;
  }
  b -= 16;
  int u = b * 256 + t;      // hcvt: 2x float4 -> 1x short8 (16B stores)
  if (u < nh8) {
    const float4* h4 = (const float4*)h;
    float4 v0 = h4[u * 2], v1 = h4[u * 2 + 1];
    short8 s;
    s[0] = (short)f2bf(v0.x); s[1] = (short)f2bf(v0.y);
    s[2] = (short)f2bf(v0.z); s[3] = (short)f2bf(v0.w);
    s[4] = (short)f2bf(v1.x); s[5] = (short)f2bf(v1.y);
    s[6] = (short)f2bf(v1.z); s[7] = (short)f2bf(v1.w);
    ((short8*)HBF)[u] = s;
  }
}

// ---- main kernel: R16 (32x32x16 MFMA) + __launch_bounds__(256,1) ----
// R16 anomaly: at (256,2) (cap 256) the allocator VOLUNTARILY targeted the
// 128-reg tier and spilled ~12 dwords/thread (WRITE_SIZE 110 MB, dur 301us)
// -- the 16-aligned floatx16 acc tuples + bq ring don't fit 128. Fix: bound
// (256,1) raises the cap to 512 so the natural ~160-176 allocation sticks.
// Occupancy is unaffected: LDS (66 KB) pins 2 blocks/CU = 2 waves/SIMD
// either way; the bound only constrained the register allocator.
// Everything else identical to R16 (HW-verified correct: same absmax).
__global__ __launch_bounds__(256, 1)
void edge_mlp3(const unsigned short* __restrict__ hbf,
               const int* __restrict__ dst,
               const int* __restrict__ src,
               const unsigned short* __restrict__ W1F,
               const unsigned short* __restrict__ W2F,
               const unsigned short* __restrict__ W3F,
               float* __restrict__ out) {
  __shared__ __align__(16) unsigned short P[64 * 256];  // dst half; then X, X2
  __shared__ __align__(16) unsigned short S[64 * 256];  // src half
  __shared__ int ioff[128];

  const int t = threadIdx.x, lane = t & 63, w = t >> 6;
  const int lq = lane >> 4, lm = lane & 15;   // 16x16 path (L3)
  const int ln = lane & 31, qh = lane >> 5;   // 32x32 path
  const int wc = w * 64;                      // wave col base
  const int m0 = blockIdx.x * 64;
  const int rbase = w * 16;

  if (t < 64)       ioff[t] = dst[m0 + t];
  else if (t < 128) ioff[t] = src[m0 + t - 64];
  __syncthreads();   // ioff visible; nothing else outstanding yet

  // ---- issue BOTH gather halves up-front: dst->P (oldest 8), src->S (newest 8)
#pragma unroll
  for (int tt = 0; tt < 8; ++tt) {
    int rl = rbase + 2 * tt + qh;
    int node = ioff[rl];
    gld16(hbf + (size_t)node * 256 + ((ln ^ sw3(rl)) << 3), &P[(rbase + 2 * tt) * 256]);
  }
#pragma unroll
  for (int tt = 0; tt < 8; ++tt) {
    int rl = rbase + 2 * tt + qh;
    int node = ioff[64 + rl];
    gld16(hbf + (size_t)node * 256 + ((ln ^ sw3(rl)) << 3), &S[(rbase + 2 * tt) * 256]);
  }

  floatx16 acc[2][2];
#pragma unroll
  for (int i = 0; i < 2; ++i)
#pragma unroll
    for (int j = 0; j < 2; ++j) acc[i][j] = (floatx16)(0.0f);

  const short8* B1 = (const short8*)W1F;
  const short8* B2 = (const short8*)W2F;

  // ---- counted wait: this wave's 8 dst loads landed; 8 src stay in flight
  asm volatile("s_waitcnt vmcnt(8)" ::: "memory");
  __builtin_amdgcn_sched_barrier(0);
  __builtin_amdgcn_s_barrier();      // RAW barrier: no vmcnt(0) drain
  __builtin_amdgcn_sched_barrier(0);

  // ---- layer1, k16-steps 0..15 (dst features) on P; mfma32(W, X) = D^T
  {
    short8 bq[2][2];
#pragma unroll
    for (int jt = 0; jt < 2; ++jt) bq[0][jt] = B1[((0 * 256 + wc + jt * 32 + ln) << 1) + qh];
#pragma unroll
    for (int jt = 0; jt < 2; ++jt) bq[1][jt] = B1[((1 * 256 + wc + jt * 32 + ln) << 1) + qh];

#pragma unroll
    for (int s = 0; s < 16; ++s) {
      short8 af[2];
#pragma unroll
      for (int i = 0; i < 2; ++i) {
        int r = i * 32 + ln;
        af[i] = *(const short8*)&P[r * 256 + (((2 * s + qh) ^ sw3(r)) << 3)];
      }
#pragma unroll
      for (int i = 0; i < 2; ++i)
#pragma unroll
        for (int j = 0; j < 2; ++j)
          acc[i][j] = __builtin_amdgcn_mfma_f32_32x32x16_bf16(bq[s & 1][j], af[i], acc[i][j], 0, 0, 0);
      if (s < 14)
#pragma unroll
        for (int jt = 0; jt < 2; ++jt)
          bq[s & 1][jt] = B1[(((s + 2) * 256 + wc + jt * 32 + ln) << 1) + qh];
    }
  }
  __syncthreads();   // vmcnt(0): src loads (already landed) + barrier

  // ---- layer1, k16-steps 16..31 (src features) on S
  {
    short8 bq[2][2];
#pragma unroll
    for (int jt = 0; jt < 2; ++jt) bq[0][jt] = B1[((16 * 256 + wc + jt * 32 + ln) << 1) + qh];
#pragma unroll
    for (int jt = 0; jt < 2; ++jt) bq[1][jt] = B1[((17 * 256 + wc + jt * 32 + ln) << 1) + qh];

#pragma unroll
    for (int s = 0; s < 16; ++s) {
      short8 af[2];
#pragma unroll
      for (int i = 0; i < 2; ++i) {
        int r = i * 32 + ln;
        af[i] = *(const short8*)&S[r * 256 + (((2 * s + qh) ^ sw3(r)) << 3)];
      }
#pragma unroll
      for (int i = 0; i < 2; ++i)
#pragma unroll
        for (int j = 0; j < 2; ++j)
          acc[i][j] = __builtin_amdgcn_mfma_f32_32x32x16_bf16(bq[s & 1][j], af[i], acc[i][j], 0, 0, 0);
      if (s < 14)
#pragma unroll
        for (int jt = 0; jt < 2; ++jt)
          bq[s & 1][jt] = B1[(((s + 18) * 256 + wc + jt * 32 + ln) << 1) + qh];
    }
  }
  // no barrier needed: E1 uses only this wave's acc, writes its own col
  // range of P, and P's last reads (L1-dst) are barrier-separated.

  // ---- Epilogue 1: relu -> X (=P). D^T map: lane = edge row i*32+ln;
  // regs 4g..4g+3 = features wc + j*32 + g*8 + 4*qh + (0..3). Pack + 8B.
#pragma unroll
  for (int i = 0; i < 2; ++i) {
    int r = i * 32 + ln;
    int swz = sw3(r);
#pragma unroll
    for (int j = 0; j < 2; ++j) {
#pragma unroll
      for (int g = 0; g < 4; ++g) {
        int c8 = (wc >> 3) + j * 4 + g;
        float v0 = fmaxf(acc[i][j][4 * g + 0], 0.0f);
        float v1 = fmaxf(acc[i][j][4 * g + 1], 0.0f);
        float v2 = fmaxf(acc[i][j][4 * g + 2], 0.0f);
        float v3 = fmaxf(acc[i][j][4 * g + 3], 0.0f);
        uint2 pv;
        pv.x = pk2bf(v0, v1);
        pv.y = pk2bf(v2, v3);
        *(uint2*)&P[r * 256 + (((c8 ^ swz) << 3) | (qh << 2))] = pv;
      }
    }
  }
#pragma unroll
  for (int i = 0; i < 2; ++i)
#pragma unroll
    for (int j = 0; j < 2; ++j) acc[i][j] = (floatx16)(0.0f);
  __syncthreads();   // X complete before L2 reads

  // ---- Layer 2: K=256, 16 k16-steps, reads X (=P), mfma32 swapped
  {
    short8 bq[2][2];
#pragma unroll
    for (int jt = 0; jt < 2; ++jt) bq[0][jt] = B2[((0 * 256 + wc + jt * 32 + ln) << 1) + qh];
#pragma unroll
    for (int jt = 0; jt < 2; ++jt) bq[1][jt] = B2[((1 * 256 + wc + jt * 32 + ln) << 1) + qh];

#pragma unroll
    for (int s = 0; s < 16; ++s) {
      short8 af[2];
#pragma unroll
      for (int i = 0; i < 2; ++i) {
        int r = i * 32 + ln;
        af[i] = *(const short8*)&P[r * 256 + (((2 * s + qh) ^ sw3(r)) << 3)];
      }
#pragma unroll
      for (int i = 0; i < 2; ++i)
#pragma unroll
        for (int j = 0; j < 2; ++j)
          acc[i][j] = __builtin_amdgcn_mfma_f32_32x32x16_bf16(bq[s & 1][j], af[i], acc[i][j], 0, 0, 0);
      if (s < 14)
#pragma unroll
        for (int jt = 0; jt < 2; ++jt)
          bq[s & 1][jt] = B2[(((s + 2) * 256 + wc + jt * 32 + ln) << 1) + qh];
    }
  }
  __syncthreads();   // all X reads done before in-place X2 overwrite

  // ---- Epilogue 2: relu -> X2 (=P, in place), packed 8B stores
#pragma unroll
  for (int i = 0; i < 2; ++i) {
    int r = i * 32 + ln;
    int swz = sw3(r);
#pragma unroll
    for (int j = 0; j < 2; ++j) {
#pragma unroll
      for (int g = 0; g < 4; ++g) {
        int c8 = (wc >> 3) + j * 4 + g;
        float v0 = fmaxf(acc[i][j][4 * g + 0], 0.0f);
        float v1 = fmaxf(acc[i][j][4 * g + 1], 0.0f);
        float v2 = fmaxf(acc[i][j][4 * g + 2], 0.0f);
        float v3 = fmaxf(acc[i][j][4 * g + 3], 0.0f);
        uint2 pv;
        pv.x = pk2bf(v0, v1);
        pv.y = pk2bf(v2, v3);
        *(uint2*)&P[r * 256 + (((c8 ^ swz) << 3) | (qh << 2))] = pv;
      }
    }
  }
  __syncthreads();   // X2 complete before L3 reads

  // ---- Layer 3: out = X2 @ W3 via 16x16 MFMA (N padded to 16) -- unchanged
  {
    floatx4 a3 = (floatx4)(0.0f);
    const short8* B3 = (const short8*)W3F;
#pragma unroll
    for (int s = 0; s < 8; ++s) {
      short8 b3 = B3[s * 64 + lane];              // 1 KB coalesced, L2-hot
      int r = w * 16 + lm, cch = s * 4 + lq;
      short8 af = *(const short8*)&P[r * 256 + ((cch ^ sw3(r)) << 3)];
      a3 = __builtin_amdgcn_mfma_f32_16x16x32_bf16(af, b3, a3, 0, 0, 0);
    }
    if (lm < 2) {
#pragma unroll
      for (int rg = 0; rg < 4; ++rg)
        out[(m0 + w * 16 + lq * 4 + rg) * 2 + lm] = a3[rg];
    }
  }
}

// ---- legacy weight-frag kernel (fallback path only, 16x16 layout) ----
__global__ void wfrag_kernel(const float* __restrict__ W,
                             unsigned short* __restrict__ out, int total) {
  int u = blockIdx.x * 256 + threadIdx.x;
  if (u >= total) return;
  int j = u & 7, kq = (u >> 3) & 3, n = (u >> 5) & 255, k32 = u >> 13;
  out[u] = f2bf(W[(k32 * 32 + kq * 8 + j) * 256 + n]);
}

// ---- fp32-gather fallback (tiny workspace) ----
__global__ __launch_bounds__(256, 2)
void edge_mlp_fb(const float* __restrict__ h,
                 const int* __restrict__ dst,
                 const int* __restrict__ src,
                 const unsigned short* __restrict__ W1F,
                 const unsigned short* __restrict__ W2F,
                 const float* __restrict__ W3,
                 float* __restrict__ out) {
  __shared__ unsigned short A[64 * 512];
  __shared__ float w3s[512];
  __shared__ int ioff[128];
  unsigned short* X = A;
  const int t = threadIdx.x, lane = t & 63, w = t >> 6;
  const int lq = lane >> 4, lm = lane & 15;
  const int m0 = blockIdx.x * 64;
  if (t < 64) ioff[t] = dst[m0 + t];
  else if (t < 128) ioff[t] = src[m0 + t - 64];
  w3s[t] = W3[t];
  w3s[t + 256] = W3[t + 256];
  __syncthreads();
  {
    const int c = lane, half = (c >= 32) ? 64 : 0, cc = c & 31;
#pragma unroll
    for (int it = 0; it < 16; ++it) {
      int r = it * 4 + w;
      int node = ioff[half + r];
      const float4* h4 = (const float4*)h;
      float4 v0 = h4[node * 64 + cc * 2], v1 = h4[node * 64 + cc * 2 + 1];
      short8 v;
      v[0] = (short)f2bf(v0.x); v[1] = (short)f2bf(v0.y);
      v[2] = (short)f2bf(v0.z); v[3] = (short)f2bf(v0.w);
      v[4] = (short)f2bf(v1.x); v[5] = (short)f2bf(v1.y);
      v[6] = (short)f2bf(v1.z); v[7] = (short)f2bf(v1.w);
      *(short8*)&A[r * 512 + ((c ^ (r & 7)) << 3)] = v;
    }
  }
  floatx4 acc[4][4];
#pragma unroll
  for (int i = 0; i < 4; ++i)
#pragma unroll
    for (int j = 0; j < 4; ++j) acc[i][j] = (floatx4)(0.0f);
  __syncthreads();
  const short8* B1 = (const short8*)W1F;
  const short8* B2 = (const short8*)W2F;
#pragma unroll
  for (int k32 = 0; k32 < 16; ++k32) {
    short8 b[4], af[4];
#pragma unroll
    for (int jt = 0; jt < 4; ++jt)
      b[jt] = B1[(k32 * 256 + w * 64 + jt * 16 + lm) * 4 + lq];
#pragma unroll
    for (int i = 0; i < 4; ++i) {
      int r = i * 16 + lm, c = k32 * 4 + lq;
      af[i] = *(const short8*)&A[r * 512 + ((c ^ (r & 7)) << 3)];
    }
#pragma unroll
    for (int i = 0; i < 4; ++i)
#pragma unroll
      for (int j = 0; j < 4; ++j)
        acc[i][j] = __builtin_amdgcn_mfma_f32_16x16x32_bf16(af[i], b[j], acc[i][j], 0, 0, 0);
  }
  __syncthreads();
#pragma unroll
  for (int i = 0; i < 4; ++i) {
    int row0 = i * 16 + lq * 4;
#pragma unroll
    for (int j = 0; j < 4; ++j) {
      int col = w * 64 + j * 16 + lm, c8 = col >> 3, ce = col & 7;
#pragma unroll
      for (int rg = 0; rg < 4; ++rg) {
        int row = row0 + rg;
        float v = acc[i][j][rg];
        v = v > 0.0f ? v : 0.0f;
        X[row * 256 + (((c8 ^ (row & 7)) << 3) | ce)] = f2bf(v);
      }
    }
  }
#pragma unroll
  for (int i = 0; i < 4; ++i)
#pragma unroll
    for (int j = 0; j < 4; ++j) acc[i][j] = (floatx4)(0.0f);
  __syncthreads();
#pragma unroll
  for (int k32 = 0; k32 < 8; ++k32) {
    short8 b[4], af[4];
#pragma unroll
    for (int jt = 0; jt < 4; ++jt)
      b[jt] = B2[(k32 * 256 + w * 64 + jt * 16 + lm) * 4 + lq];
#pragma unroll
    for (int i = 0; i < 4; ++i) {
      int r = i * 16 + lm, c = k32 * 4 + lq;
      af[i] = *(const short8*)&X[r * 256 + ((c ^ (r & 7)) << 3)];
    }
#pragma unroll
    for (int i = 0; i < 4; ++i)
#pragma unroll
      for (int j = 0; j < 4; ++j)
        acc[i][j] = __builtin_amdgcn_mfma_f32_16x16x32_bf16(af[i], b[j], acc[i][j], 0, 0, 0);
  }
  __syncthreads();
#pragma unroll
  for (int i = 0; i < 4; ++i) {
    int row0 = i * 16 + lq * 4;
#pragma unroll
    for (int j = 0; j < 4; ++j) {
      int col = w * 64 + j * 16 + lm, c8 = col >> 3, ce = col & 7;
#pragma unroll
      for (int rg = 0; rg < 4; ++rg) {
        int row = row0 + rg;
        float v = acc[i][j][rg];
        v = v > 0.0f ? v : 0.0f;
        X[row * 256 + (((c8 ^ (row & 7)) << 3) | ce)] = f2bf(v);
      }
    }
  }
  __syncthreads();
  {
    int r = t >> 2, o = (t >> 1) & 1, hh = t & 1;
    float s = 0.0f;
#pragma unroll
    for (int it = 0; it < 16; ++it) {
      int c = hh * 16 + it;
      short8 xv = *(const short8*)&X[r * 256 + ((c ^ (r & 7)) << 3)];
#pragma unroll
      for (int e = 0; e < 8; ++e)
        s += bf2f((unsigned short)xv[e]) * w3s[((c << 3) + e) * 2 + o];
    }
    s += __shfl_xor(s, 1);
    if (hh == 0) out[(m0 + r) * 2 + o] = s;
  }
}

extern "C" void kernel_launch(void* const* d_in, const int* in_sizes, int n_in,
                              void* d_out, int out_size, void* d_ws, size_t ws_size,
                              hipStream_t stream) {
  const float* h   = (const float*)d_in[0];
  const int*   dst = (const int*)d_in[1];
  const int*   src = (const int*)d_in[2];
  const float* W1  = (const float*)d_in[3];
  const float* W2  = (const float*)d_in[4];
  const float* W3  = (const float*)d_in[5];
  float* out = (float*)d_out;

  const int h_elems = in_sizes[0];
  const int n_pairs = in_sizes[1];
  const int ntiles  = n_pairs / 64;

  const size_t hbf_elems = (size_t)h_elems;
  const bool use_hbf =
      ws_size >= (hbf_elems + 131072 + 65536 + 4096) * sizeof(unsigned short);

  unsigned short* HBF = (unsigned short*)d_ws;
  unsigned short* W1F = HBF + hbf_elems;
  unsigned short* W2F = W1F + 131072;
  unsigned short* W3F = W2F + 65536;

  if (use_hbf) {
    int nh8 = h_elems / 8;
    int grid = 512 + 256 + 16 + (nh8 + 255) / 256;
    prep_kernel<<<grid, 256, 0, stream>>>(h, W1, W2, W3, HBF, W1F, W2F, W3F, nh8);
    edge_mlp3<<<ntiles, 256, 0, stream>>>(HBF, dst, src, W1F, W2F, W3F, out);
  } else {
    unsigned short* W1Fb = (unsigned short*)d_ws;
    unsigned short* W2Fb = W1Fb + 131072;
    wfrag_kernel<<<512, 256, 0, stream>>>(W1, W1Fb, 131072);
    wfrag_kernel<<<256, 256, 0, stream>>>(W2, W2Fb, 65536);
    edge_mlp_fb<<<ntiles, 256, 0, stream>>>(h, dst, src, W1Fb, W2Fb, W3, out);
  }
}

// Round 18
// 403.527 us; speedup vs baseline: 1.3722x; 1.0614x over previous
//
#include <hip/hip_runtime.h>
#include <stdint.h>

typedef __attribute__((ext_vector_type(8))) short short8;
typedef __attribute__((ext_vector_type(4))) float floatx4;

__device__ __forceinline__ unsigned short f2bf(float x) {
  unsigned int u = __float_as_uint(x);
  u += 0x7fffu + ((u >> 16) & 1u);   // RNE
  return (unsigned short)(u >> 16);
}
__device__ __forceinline__ float bf2f(unsigned short b) {
  return __uint_as_float(((unsigned int)b) << 16);
}
// packed pair: two RNE bf16 in one u32 (pure int ops, no asm)
__device__ __forceinline__ unsigned int pk2bf(float lo, float hi) {
  return (unsigned int)f2bf(lo) | ((unsigned int)f2bf(hi) << 16);
}
// row swizzle: spreads same-column reads of consecutive rows across bank-quads.
__device__ __forceinline__ int sw3(int r) { return (r & 7) ^ (((r >> 3) & 1) * 3); }

// direct global->LDS (16B/lane). LDS dest = uniform base + lane*16 (linear);
// swizzle is applied on the per-lane GLOBAL address instead (m173 pattern).
__device__ __forceinline__ void gld16(const unsigned short* g, unsigned short* l) {
  __builtin_amdgcn_global_load_lds(
      (const __attribute__((address_space(1))) void*)g,
      (__attribute__((address_space(3))) void*)l, 16, 0, 0);
}

// ---- unified prologue: weight frags + h bf16 table ----
// GRID-STRIDE REWORK (R18): the old prep launched 13,284 one-shot blocks;
// at ~100 blocks/us command-processor dispatch rate that is ~130 us of pure
// dispatch exposure (matches the constant ~105-147 us total-vs-kernel gap
// across all rounds; hcvt's memory cost is only ~25 us). New grid = 2048
// blocks, all co-resident in one dispatch wave; hcvt blocks grid-stride
// (~10 short8s per thread).
// W1F/W2F B-frag layout (16x16x32): u=((k32*256+n)*4+kq)*8+j holds
//   W[k32*32+kq*8+j][n]
// W3F B-frag layout (N padded 2->16): u=(k32*64+L)*8+j holds
//   W3[k32*32+(L>>4)*8+j][L&15] or 0
#define HCVT_BLOCKS 1264
__global__ void prep_kernel(const float* __restrict__ h, const float* __restrict__ W1,
                            const float* __restrict__ W2, const float* __restrict__ W3,
                            unsigned short* __restrict__ HBF, unsigned short* __restrict__ W1F,
                            unsigned short* __restrict__ W2F, unsigned short* __restrict__ W3F,
                            int nh8) {
  const int t = threadIdx.x;
  int b = blockIdx.x;
  if (b < 512) {            // W1F: 131072 elems
    int u = b * 256 + t;
    int j = u & 7, kq = (u >> 3) & 3, n = (u >> 5) & 255, k32 = u >> 13;
    W1F[u] = f2bf(W1[(k32 * 32 + kq * 8 + j) * 256 + n]);
    return;
  }
  b -= 512;
  if (b < 256) {            // W2F: 65536 elems
    int u = b * 256 + t;
    int j = u & 7, kq = (u >> 3) & 3, n = (u >> 5) & 255, k32 = u >> 13;
    W2F[u] = f2bf(W2[(k32 * 32 + kq * 8 + j) * 256 + n]);
    return;
  }
  b -= 256;
  if (b < 16) {             // W3F: 4096 elems
    int u = b * 256 + t;
    int j = u & 7, L = (u >> 3) & 63, k32 = u >> 9;
    int n = L & 15, kq = L >> 4;
    W3F[u] = (n < 2) ? f2bf(W3[(k32 * 32 + kq * 8 + j) * 2 + n]) : (unsigned short)0;
    return;
  }
  b -= 16;
  // hcvt: grid-stride, 2x float4 -> 1x short8 (16B stores) per element
  const float4* h4 = (const float4*)h;
  const int stride = HCVT_BLOCKS * 256;
  for (int u = b * 256 + t; u < nh8; u += stride) {
    float4 v0 = h4[u * 2], v1 = h4[u * 2 + 1];
    short8 s;
    s[0] = (short)f2bf(v0.x); s[1] = (short)f2bf(v0.y);
    s[2] = (short)f2bf(v0.z); s[3] = (short)f2bf(v0.w);
    s[4] = (short)f2bf(v1.x); s[5] = (short)f2bf(v1.y);
    s[6] = (short)f2bf(v1.z); s[7] = (short)f2bf(v1.w);
    ((short8*)HBF)[u] = s;
  }
}

// ---- main kernel: R11 verbatim (best verified: 276 us) ----
// 4 waves / 256 thr / __launch_bounds__(256,2), 64x64 wave tiles, dual
// 32KB buffers, up-front dual gather with counted vmcnt(8) + raw barrier,
// swapped-operand MFMA (lane holds 4 consecutive feature cols of one edge
// row -> packed 8B epilogue stores), bq[2][4] depth-2 ring.
// Session-closed veins: occupancy (R1/R2/R6/R9/R13/R14: needs ~150+ arch
// regs -> pinned at 2 waves/SIMD; every cap/tile route spills or doubles
// LDS traffic), af software-pipeline (R12: compiler already schedules),
// 32x32 MFMA (R16/R17: equal at best).
__global__ __launch_bounds__(256, 2)
void edge_mlp3(const unsigned short* __restrict__ hbf,
               const int* __restrict__ dst,
               const int* __restrict__ src,
               const unsigned short* __restrict__ W1F,
               const unsigned short* __restrict__ W2F,
               const unsigned short* __restrict__ W3F,
               float* __restrict__ out) {
  __shared__ __align__(16) unsigned short P[64 * 256];  // dst half; then X, X2
  __shared__ __align__(16) unsigned short S[64 * 256];  // src half
  __shared__ int ioff[128];

  const int t = threadIdx.x, lane = t & 63, w = t >> 6;
  const int lq = lane >> 4, lm = lane & 15;
  const int m0 = blockIdx.x * 64;
  const int mm = lane & 31, rh = lane >> 5, rbase = w * 16;

  if (t < 64)       ioff[t] = dst[m0 + t];
  else if (t < 128) ioff[t] = src[m0 + t - 64];
  __syncthreads();   // ioff visible; nothing else outstanding yet

  // ---- issue BOTH gather halves up-front: dst->P (oldest 8), src->S (newest 8)
#pragma unroll
  for (int tt = 0; tt < 8; ++tt) {
    int rl = rbase + 2 * tt + rh;
    int node = ioff[rl];
    gld16(hbf + (size_t)node * 256 + ((mm ^ sw3(rl)) << 3), &P[(rbase + 2 * tt) * 256]);
  }
#pragma unroll
  for (int tt = 0; tt < 8; ++tt) {
    int rl = rbase + 2 * tt + rh;
    int node = ioff[64 + rl];
    gld16(hbf + (size_t)node * 256 + ((mm ^ sw3(rl)) << 3), &S[(rbase + 2 * tt) * 256]);
  }

  floatx4 acc[4][4];
#pragma unroll
  for (int i = 0; i < 4; ++i)
#pragma unroll
    for (int j = 0; j < 4; ++j) acc[i][j] = (floatx4)(0.0f);

  const short8* B1 = (const short8*)W1F;
  const short8* B2 = (const short8*)W2F;

  // ---- counted wait: this wave's 8 dst loads landed; 8 src stay in flight
  asm volatile("s_waitcnt vmcnt(8)" ::: "memory");
  __builtin_amdgcn_sched_barrier(0);
  __builtin_amdgcn_s_barrier();      // RAW barrier: no vmcnt(0) drain
  __builtin_amdgcn_sched_barrier(0);

  // ---- layer1, k-steps 0..7 (dst features) on P; SWAPPED: mfma(bq, af, acc)
  {
    short8 bq[2][4];
#pragma unroll
    for (int jt = 0; jt < 4; ++jt) bq[0][jt] = B1[(0 * 256 + w * 64 + jt * 16 + lm) * 4 + lq];
#pragma unroll
    for (int jt = 0; jt < 4; ++jt) bq[1][jt] = B1[(1 * 256 + w * 64 + jt * 16 + lm) * 4 + lq];

#pragma unroll
    for (int s = 0; s < 8; ++s) {
#pragma unroll
      for (int i = 0; i < 4; ++i) {
        int r = i * 16 + lm, c = s * 4 + lq;
        short8 af = *(const short8*)&P[r * 256 + ((c ^ sw3(r)) << 3)];
#pragma unroll
        for (int j = 0; j < 4; ++j)
          acc[i][j] = __builtin_amdgcn_mfma_f32_16x16x32_bf16(bq[s & 1][j], af, acc[i][j], 0, 0, 0);
      }
      if (s < 6)
#pragma unroll
        for (int jt = 0; jt < 4; ++jt)
          bq[s & 1][jt] = B1[((s + 2) * 256 + w * 64 + jt * 16 + lm) * 4 + lq];
    }
  }
  __syncthreads();   // vmcnt(0): src loads (already landed) + barrier

  // ---- layer1, k-steps 8..15 (src features) on S
  {
    short8 bq[2][4];
#pragma unroll
    for (int jt = 0; jt < 4; ++jt) bq[0][jt] = B1[(8 * 256 + w * 64 + jt * 16 + lm) * 4 + lq];
#pragma unroll
    for (int jt = 0; jt < 4; ++jt) bq[1][jt] = B1[(9 * 256 + w * 64 + jt * 16 + lm) * 4 + lq];

#pragma unroll
    for (int s = 0; s < 8; ++s) {
#pragma unroll
      for (int i = 0; i < 4; ++i) {
        int r = i * 16 + lm, c = s * 4 + lq;
        short8 af = *(const short8*)&S[r * 256 + ((c ^ sw3(r)) << 3)];
#pragma unroll
        for (int j = 0; j < 4; ++j)
          acc[i][j] = __builtin_amdgcn_mfma_f32_16x16x32_bf16(bq[s & 1][j], af, acc[i][j], 0, 0, 0);
      }
      if (s < 6)
#pragma unroll
        for (int jt = 0; jt < 4; ++jt)
          bq[s & 1][jt] = B1[((s + 10) * 256 + w * 64 + jt * 16 + lm) * 4 + lq];
    }
  }
  // no barrier needed here: E1 uses only this wave's acc, writes its own
  // column range of P, and P's last reads (L1-dst) are barrier-separated.

  // ---- Epilogue 1: relu -> X (=P). D^T map: lane holds edge row i*16+lm,
  // 4 consecutive feature cols (w*64 + j*16 + lq*4 + rg). Pack + 8B store.
#pragma unroll
  for (int i = 0; i < 4; ++i) {
    int row = i * 16 + lm;
    int swz = sw3(row);
#pragma unroll
    for (int j = 0; j < 4; ++j) {
      int cb = w * 64 + j * 16 + lq * 4;
      int c8 = cb >> 3, ce = cb & 7;
      float v0 = fmaxf(acc[i][j][0], 0.0f);
      float v1 = fmaxf(acc[i][j][1], 0.0f);
      float v2 = fmaxf(acc[i][j][2], 0.0f);
      float v3 = fmaxf(acc[i][j][3], 0.0f);
      uint2 pv;
      pv.x = pk2bf(v0, v1);
      pv.y = pk2bf(v2, v3);
      *(uint2*)&P[row * 256 + (((c8 ^ swz) << 3) | ce)] = pv;
    }
  }
#pragma unroll
  for (int i = 0; i < 4; ++i)
#pragma unroll
    for (int j = 0; j < 4; ++j) acc[i][j] = (floatx4)(0.0f);
  __syncthreads();   // X complete before L2 reads

  // ---- Layer 2: K=256, 8 k-steps, B-ring depth 2, reads X (=P), swapped
  {
    short8 bq[2][4];
#pragma unroll
    for (int jt = 0; jt < 4; ++jt) bq[0][jt] = B2[(0 * 256 + w * 64 + jt * 16 + lm) * 4 + lq];
#pragma unroll
    for (int jt = 0; jt < 4; ++jt) bq[1][jt] = B2[(1 * 256 + w * 64 + jt * 16 + lm) * 4 + lq];

#pragma unroll
    for (int s = 0; s < 8; ++s) {
#pragma unroll
      for (int i = 0; i < 4; ++i) {
        int r = i * 16 + lm, c = s * 4 + lq;
        short8 af = *(const short8*)&P[r * 256 + ((c ^ sw3(r)) << 3)];
#pragma unroll
        for (int j = 0; j < 4; ++j)
          acc[i][j] = __builtin_amdgcn_mfma_f32_16x16x32_bf16(bq[s & 1][j], af, acc[i][j], 0, 0, 0);
      }
      if (s < 6)
#pragma unroll
        for (int jt = 0; jt < 4; ++jt)
          bq[s & 1][jt] = B2[((s + 2) * 256 + w * 64 + jt * 16 + lm) * 4 + lq];
    }
  }
  __syncthreads();   // all X reads done before in-place X2 overwrite

  // ---- Epilogue 2: relu -> X2 (=P, in place), packed 8B stores
#pragma unroll
  for (int i = 0; i < 4; ++i) {
    int row = i * 16 + lm;
    int swz = sw3(row);
#pragma unroll
    for (int j = 0; j < 4; ++j) {
      int cb = w * 64 + j * 16 + lq * 4;
      int c8 = cb >> 3, ce = cb & 7;
      float v0 = fmaxf(acc[i][j][0], 0.0f);
      float v1 = fmaxf(acc[i][j][1], 0.0f);
      float v2 = fmaxf(acc[i][j][2], 0.0f);
      float v3 = fmaxf(acc[i][j][3], 0.0f);
      uint2 pv;
      pv.x = pk2bf(v0, v1);
      pv.y = pk2bf(v2, v3);
      *(uint2*)&P[row * 256 + (((c8 ^ swz) << 3) | ce)] = pv;
    }
  }
  __syncthreads();   // X2 complete before L3 reads

  // ---- Layer 3: out = X2 @ W3 via MFMA (N padded to 16; cols 0,1 valid)
  // unswapped: D map row=quad*4+reg (edge), col=lane&15 (out idx)
  {
    floatx4 a3 = (floatx4)(0.0f);
    const short8* B3 = (const short8*)W3F;
#pragma unroll
    for (int s = 0; s < 8; ++s) {
      short8 b3 = B3[s * 64 + lane];              // 1 KB coalesced, L2-hot
      int r = w * 16 + lm, cch = s * 4 + lq;
      short8 af = *(const short8*)&P[r * 256 + ((cch ^ sw3(r)) << 3)];
      a3 = __builtin_amdgcn_mfma_f32_16x16x32_bf16(af, b3, a3, 0, 0, 0);
    }
    if (lm < 2) {
#pragma unroll
      for (int rg = 0; rg < 4; ++rg)
        out[(m0 + w * 16 + lq * 4 + rg) * 2 + lm] = a3[rg];
    }
  }
}

// ---- legacy weight-frag kernel (fallback path only) ----
__global__ void wfrag_kernel(const float* __restrict__ W,
                             unsigned short* __restrict__ out, int total) {
  int u = blockIdx.x * 256 + threadIdx.x;
  if (u >= total) return;
  int j = u & 7, kq = (u >> 3) & 3, n = (u >> 5) & 255, k32 = u >> 13;
  out[u] = f2bf(W[(k32 * 32 + kq * 8 + j) * 256 + n]);
}

// ---- fp32-gather fallback (tiny workspace) ----
__global__ __launch_bounds__(256, 2)
void edge_mlp_fb(const float* __restrict__ h,
                 const int* __restrict__ dst,
                 const int* __restrict__ src,
                 const unsigned short* __restrict__ W1F,
                 const unsigned short* __restrict__ W2F,
                 const float* __restrict__ W3,
                 float* __restrict__ out) {
  __shared__ unsigned short A[64 * 512];
  __shared__ float w3s[512];
  __shared__ int ioff[128];
  unsigned short* X = A;
  const int t = threadIdx.x, lane = t & 63, w = t >> 6;
  const int lq = lane >> 4, lm = lane & 15;
  const int m0 = blockIdx.x * 64;
  if (t < 64) ioff[t] = dst[m0 + t];
  else if (t < 128) ioff[t] = src[m0 + t - 64];
  w3s[t] = W3[t];
  w3s[t + 256] = W3[t + 256];
  __syncthreads();
  {
    const int c = lane, half = (c >= 32) ? 64 : 0, cc = c & 31;
#pragma unroll
    for (int it = 0; it < 16; ++it) {
      int r = it * 4 + w;
      int node = ioff[half + r];
      const float4* h4 = (const float4*)h;
      float4 v0 = h4[node * 64 + cc * 2], v1 = h4[node * 64 + cc * 2 + 1];
      short8 v;
      v[0] = (short)f2bf(v0.x); v[1] = (short)f2bf(v0.y);
      v[2] = (short)f2bf(v0.z); v[3] = (short)f2bf(v0.w);
      v[4] = (short)f2bf(v1.x); v[5] = (short)f2bf(v1.y);
      v[6] = (short)f2bf(v1.z); v[7] = (short)f2bf(v1.w);
      *(short8*)&A[r * 512 + ((c ^ (r & 7)) << 3)] = v;
    }
  }
  floatx4 acc[4][4];
#pragma unroll
  for (int i = 0; i < 4; ++i)
#pragma unroll
    for (int j = 0; j < 4; ++j) acc[i][j] = (floatx4)(0.0f);
  __syncthreads();
  const short8* B1 = (const short8*)W1F;
  const short8* B2 = (const short8*)W2F;
#pragma unroll
  for (int k32 = 0; k32 < 16; ++k32) {
    short8 b[4], af[4];
#pragma unroll
    for (int jt = 0; jt < 4; ++jt)
      b[jt] = B1[(k32 * 256 + w * 64 + jt * 16 + lm) * 4 + lq];
#pragma unroll
    for (int i = 0; i < 4; ++i) {
      int r = i * 16 + lm, c = k32 * 4 + lq;
      af[i] = *(const short8*)&A[r * 512 + ((c ^ (r & 7)) << 3)];
    }
#pragma unroll
    for (int i = 0; i < 4; ++i)
#pragma unroll
      for (int j = 0; j < 4; ++j)
        acc[i][j] = __builtin_amdgcn_mfma_f32_16x16x32_bf16(af[i], b[j], acc[i][j], 0, 0, 0);
  }
  __syncthreads();
#pragma unroll
  for (int i = 0; i < 4; ++i) {
    int row0 = i * 16 + lq * 4;
#pragma unroll
    for (int j = 0; j < 4; ++j) {
      int col = w * 64 + j * 16 + lm, c8 = col >> 3, ce = col & 7;
#pragma unroll
      for (int rg = 0; rg < 4; ++rg) {
        int row = row0 + rg;
        float v = acc[i][j][rg];
        v = v > 0.0f ? v : 0.0f;
        X[row * 256 + (((c8 ^ (row & 7)) << 3) | ce)] = f2bf(v);
      }
    }
  }
#pragma unroll
  for (int i = 0; i < 4; ++i)
#pragma unroll
    for (int j = 0; j < 4; ++j) acc[i][j] = (floatx4)(0.0f);
  __syncthreads();
#pragma unroll
  for (int k32 = 0; k32 < 8; ++k32) {
    short8 b[4], af[4];
#pragma unroll
    for (int jt = 0; jt < 4; ++jt)
      b[jt] = B2[(k32 * 256 + w * 64 + jt * 16 + lm) * 4 + lq];
#pragma unroll
    for (int i = 0; i < 4; ++i) {
      int r = i * 16 + lm, c = k32 * 4 + lq;
      af[i] = *(const short8*)&X[r * 256 + ((c ^ (r & 7)) << 3)];
    }
#pragma unroll
    for (int i = 0; i < 4; ++i)
#pragma unroll
      for (int j = 0; j < 4; ++j)
        acc[i][j] = __builtin_amdgcn_mfma_f32_16x16x32_bf16(af[i], b[j], acc[i][j], 0, 0, 0);
  }
  __syncthreads();
#pragma unroll
  for (int i = 0; i < 4; ++i) {
    int row0 = i * 16 + lq * 4;
#pragma unroll
    for (int j = 0; j < 4; ++j) {
      int col = w * 64 + j * 16 + lm, c8 = col >> 3, ce = col & 7;
#pragma unroll
      for (int rg = 0; rg < 4; ++rg) {
        int row = row0 + rg;
        float v = acc[i][j][rg];
        v = v > 0.0f ? v : 0.0f;
        X[row * 256 + (((c8 ^ (row & 7)) << 3) | ce)] = f2bf(v);
      }
    }
  }
  __syncthreads();
  {
    int r = t >> 2, o = (t >> 1) & 1, hh = t & 1;
    float s = 0.0f;
#pragma unroll
    for (int it = 0; it < 16; ++it) {
      int c = hh * 16 + it;
      short8 xv = *(const short8*)&X[r * 256 + ((c ^ (r & 7)) << 3)];
#pragma unroll
      for (int e = 0; e < 8; ++e)
        s += bf2f((unsigned short)xv[e]) * w3s[((c << 3) + e) * 2 + o];
    }
    s += __shfl_xor(s, 1);
    if (hh == 0) out[(m0 + r) * 2 + o] = s;
  }
}

extern "C" void kernel_launch(void* const* d_in, const int* in_sizes, int n_in,
                              void* d_out, int out_size, void* d_ws, size_t ws_size,
                              hipStream_t stream) {
  const float* h   = (const float*)d_in[0];
  const int*   dst = (const int*)d_in[1];
  const int*   src = (const int*)d_in[2];
  const float* W1  = (const float*)d_in[3];
  const float* W2  = (const float*)d_in[4];
  const float* W3  = (const float*)d_in[5];
  float* out = (float*)d_out;

  const int h_elems = in_sizes[0];
  const int n_pairs = in_sizes[1];
  const int ntiles  = n_pairs / 64;

  const size_t hbf_elems = (size_t)h_elems;
  const bool use_hbf =
      ws_size >= (hbf_elems + 131072 + 65536 + 4096) * sizeof(unsigned short);

  unsigned short* HBF = (unsigned short*)d_ws;
  unsigned short* W1F = HBF + hbf_elems;
  unsigned short* W2F = W1F + 131072;
  unsigned short* W3F = W2F + 65536;

  if (use_hbf) {
    int nh8 = h_elems / 8;
    int grid = 512 + 256 + 16 + HCVT_BLOCKS;   // 2048: one dispatch wave
    prep_kernel<<<grid, 256, 0, stream>>>(h, W1, W2, W3, HBF, W1F, W2F, W3F, nh8);
    edge_mlp3<<<ntiles, 256, 0, stream>>>(HBF, dst, src, W1F, W2F, W3F, out);
  } else {
    unsigned short* W1Fb = (unsigned short*)d_ws;
    unsigned short* W2Fb = W1Fb + 131072;
    wfrag_kernel<<<512, 256, 0, stream>>>(W1, W1Fb, 131072);
    wfrag_kernel<<<256, 256, 0, stream>>>(W2, W2Fb, 65536);
    edge_mlp_fb<<<ntiles, 256, 0, stream>>>(h, dst, src, W1Fb, W2Fb, W3, out);
  }
}